// Round 4
// baseline (464.283 us; speedup 1.0000x reference)
//
#include <hip/hip_runtime.h>

// FastMaskedDense1D.update_site  — skinny GEMM  y = A @ K + bias[index]
//   A: (8192 batch, 4800 k)  from cache[:, :299, :] with row 299 <- inputs
//   K: (4800, 16)            strided slice of kernel (row stride 8192 floats)
// Memory-bound: 157 MB A-read @ 6.3 TB/s => ~25 us floor.
//
// R1: packed K -> contiguous ws buffer (killed 32KB-stride L2 set-thrash).
// R2: K in LDS, 16 waves/CU                                  (~135 -> ~60 us)
// R3: A global->reg, 4-row K reuse — NEUTRAL: barrier-locked chunk pipeline
//     with a full vmcnt drain per chunk was the real limiter, not K's home.
// R4: barrier-free streaming. K packed TRANSPOSED (kpT[f][k]) so a wave's
//     K-load is a 256B contiguous span (no scatter, no LDS, no main-loop
//     __syncthreads). MB=8, 1024 blocks, 16 independent waves/CU, each with
//     one-stripe-ahead A prefetch. Only one barrier left (final combine).

#define EXCLUSIVE 1
#define SIZEV     512
#define NF        16
#define NIF       16
#define KROW      (SIZEV * NF)    // kernel row stride in floats (8192)
#define CROW      (SIZEV * NIF)   // cache per-batch stride in floats (8192)
#define MB        8               // batch rows per block
#define NW        4               // waves per block (pure k-split)
#define KP        8192            // kpT row stride in floats (max KTpad)

__device__ __forceinline__ float4 red4(float4 v, int m) {
    v.x += __shfl_xor(v.x, m, 64);
    v.y += __shfl_xor(v.y, m, 64);
    v.z += __shfl_xor(v.z, m, 64);
    v.w += __shfl_xor(v.w, m, 64);
    return v;
}

// Gather the used K slice TRANSPOSED into kpT[f][k] (16 rows, KP stride).
// Zero-pad k in [KT, KTpad) so fmd's last-stripe over-reach reads zeros.
__global__ __launch_bounds__(256) void pack_kt(
    const float* __restrict__ kern,
    const int*   __restrict__ idxp,
    float*       __restrict__ kpT)
{
    const int index = *idxp;
    const int jc = index - EXCLUSIVE + 1;
    const int KT = (jc > 0) ? jc * NIF : 0;          // valid packed k (4800)
    const int KTpad = (KT + 255) & ~255;             // stripe-safe reach
    const int t = blockIdx.x * blockDim.x + threadIdx.x;
    const int r = t >> 4;                            // k index
    const int f = t & 15;                            // feature
    if (r < KTpad) {
        float v = 0.f;
        if (r < KT)
            v = kern[(size_t)r * KROW + (size_t)index * NF + f];  // coalesced 64B rows
        kpT[(size_t)f * KP + r] = v;
    }
}

__global__ __launch_bounds__(256, 4) void fmd_kernel(
    const float* __restrict__ inputs,   // (B, 16)
    const float* __restrict__ cache,    // (B, 512, 16)
    const float* __restrict__ kpT,      // transposed K: (16, KP) in workspace
    const float* __restrict__ bias,     // (512, 16)
    const int*   __restrict__ idxp,     // scalar
    float*       __restrict__ out)      // (B, 16)
{
    __shared__ float Red[NW * MB * NF];   // 2 KB: cross-wave combine

    const int index = *idxp;
    const int jc = index - EXCLUSIVE + 1;
    const int KM = (jc > 0) ? (jc - 1) * NIF : 0;   // cache-sourced k count (mult of 16)

    const int tid  = threadIdx.x;
    const int lane = tid & 63;
    const int ks   = tid >> 6;      // wave 0..3 = pure k-split
    const int kq   = lane & 15;     // which 4-k group within a 64-k stripe
    const int rq   = lane >> 4;     // row pair 0..3
    const int row0 = blockIdx.x * MB;

    float acc[2][16];
    #pragma unroll
    for (int r = 0; r < 2; ++r)
        #pragma unroll
        for (int f = 0; f < 16; ++f)
            acc[r][f] = 0.f;

    // lane's A base: rows row0 + rq*2 + r, cols k0 + 4*kq .. +3
    const float* Abase = cache + (size_t)(row0 + rq * 2) * CROW + 4 * kq;

    float4 aR[2], aN[2];
    int k0 = 64 * ks;                       // stripes: k0 = 64*ks + 256*s

    if (k0 < KM) {
        #pragma unroll
        for (int r = 0; r < 2; ++r)
            aR[r] = *(const float4*)(Abase + (size_t)r * CROW + k0);

        for (; k0 < KM; k0 += 4 * 64) {
            const int kn = k0 + 4 * 64;
            if (kn < KM) {                  // prefetch next stripe's A
                #pragma unroll
                for (int r = 0; r < 2; ++r)
                    aN[r] = *(const float4*)(Abase + (size_t)r * CROW + kn);
            }

            // mask the (single) partial stripe: lane's k's are k0+4kq+j
            float4 aC[2];
            aC[0] = aR[0]; aC[1] = aR[1];
            const int nv = KM - k0;
            if (nv < 64) {
                const int rem = nv - 4 * kq;   // #valid components (may be <=0)
                #pragma unroll
                for (int r = 0; r < 2; ++r) {
                    if (rem <= 0) { aC[r].x = 0.f; aC[r].y = 0.f; aC[r].z = 0.f; aC[r].w = 0.f; }
                    else {
                        if (rem < 2) aC[r].y = 0.f;
                        if (rem < 3) aC[r].z = 0.f;
                        if (rem < 4) aC[r].w = 0.f;
                    }
                }
            }

            // K: two feature-halves of 8 to cap live VGPRs. Each load is a
            // contiguous float4 of k (kpT layout) -> 256B/instr coalesced.
            #pragma unroll
            for (int h = 0; h < 2; ++h) {
                float4 kT[8];
                #pragma unroll
                for (int fi = 0; fi < 8; ++fi)
                    kT[fi] = *(const float4*)&kpT[(size_t)(8 * h + fi) * KP + k0 + 4 * kq];
                #pragma unroll
                for (int r = 0; r < 2; ++r) {
                    #pragma unroll
                    for (int fi = 0; fi < 8; ++fi) {
                        const int f = 8 * h + fi;
                        acc[r][f] = fmaf(aC[r].x, kT[fi].x, acc[r][f]);
                        acc[r][f] = fmaf(aC[r].y, kT[fi].y, acc[r][f]);
                        acc[r][f] = fmaf(aC[r].z, kT[fi].z, acc[r][f]);
                        acc[r][f] = fmaf(aC[r].w, kT[fi].w, acc[r][f]);
                    }
                }
            }

            if (kn < KM) { aR[0] = aN[0]; aR[1] = aN[1]; }
        }
    }

    // ---- epilogue: k-row jc-1 comes from `inputs` (ks==0 waves only) ----
    if (jc > 0 && ks == 0) {
        const int kr = (jc - 1) * NIF + kq;     // < KT, valid in kpT
        float kv[16];
        #pragma unroll
        for (int f = 0; f < 16; ++f)
            kv[f] = kpT[(size_t)f * KP + kr];
        #pragma unroll
        for (int r = 0; r < 2; ++r) {
            const float a = inputs[(size_t)(row0 + rq * 2 + r) * NIF + kq];
            #pragma unroll
            for (int f = 0; f < 16; ++f)
                acc[r][f] = fmaf(a, kv[f], acc[r][f]);
        }
    }

    // ---- butterfly reduce over the 16 kq lanes ----
    #pragma unroll
    for (int m = 1; m <= 8; m <<= 1) {
        #pragma unroll
        for (int r = 0; r < 2; ++r) {
            float4 v0 = make_float4(acc[r][0],  acc[r][1],  acc[r][2],  acc[r][3]);
            float4 v1 = make_float4(acc[r][4],  acc[r][5],  acc[r][6],  acc[r][7]);
            float4 v2 = make_float4(acc[r][8],  acc[r][9],  acc[r][10], acc[r][11]);
            float4 v3 = make_float4(acc[r][12], acc[r][13], acc[r][14], acc[r][15]);
            v0 = red4(v0, m); v1 = red4(v1, m); v2 = red4(v2, m); v3 = red4(v3, m);
            acc[r][0]=v0.x;  acc[r][1]=v0.y;  acc[r][2]=v0.z;  acc[r][3]=v0.w;
            acc[r][4]=v1.x;  acc[r][5]=v1.y;  acc[r][6]=v1.z;  acc[r][7]=v1.w;
            acc[r][8]=v2.x;  acc[r][9]=v2.y;  acc[r][10]=v2.z; acc[r][11]=v2.w;
            acc[r][12]=v3.x; acc[r][13]=v3.y; acc[r][14]=v3.z; acc[r][15]=v3.w;
        }
    }

    // ---- lanes kq<8 write one float4: row rq*2+(kq&1), quad kq>>1 ----
    if (kq < 8) {
        const int r = kq & 1;
        const int q = kq >> 1;
        float4 v = make_float4(0.f, 0.f, 0.f, 0.f);
        #pragma unroll
        for (int rr = 0; rr < 2; ++rr)
            #pragma unroll
            for (int qq = 0; qq < 4; ++qq)
                if (rr == r && qq == q)
                    v = make_float4(acc[rr][4*qq], acc[rr][4*qq+1],
                                    acc[rr][4*qq+2], acc[rr][4*qq+3]);
        const int row = rq * 2 + r;
        *(float4*)&Red[ks * (MB * NF) + row * NF + 4 * q] = v;
    }
    __syncthreads();

    // ---- combine NW waves + bias, store ----
    if (tid < MB * NF) {
        const int f = tid & 15;
        float s = bias[(size_t)index * NF + f];
        #pragma unroll
        for (int ww = 0; ww < NW; ++ww)
            s += Red[ww * (MB * NF) + tid];
        out[(size_t)row0 * NF + tid] = s;
    }
}

extern "C" void kernel_launch(void* const* d_in, const int* in_sizes, int n_in,
                              void* d_out, int out_size, void* d_ws, size_t ws_size,
                              hipStream_t stream) {
    const float* inputs = (const float*)d_in[0];
    const float* cache  = (const float*)d_in[1];
    const float* kern   = (const float*)d_in[2];
    const float* bias   = (const float*)d_in[3];
    const int*   idxp   = (const int*)d_in[4];
    float*       out    = (float*)d_out;
    float*       kpT    = (float*)d_ws;          // transposed K, 16*8192*4 = 512 KB

    const int batch = in_sizes[0] / NIF;         // 8192
    const int grid  = batch / MB;                // 1024 blocks (4/CU, 16 waves/CU)

    pack_kt<<<(SIZEV * NIF * NF) / 256, 256, 0, stream>>>(kern, idxp, kpT);
    fmd_kernel<<<grid, 256, 0, stream>>>(inputs, cache, kpT, bias, idxp, out);
}